// Round 11
// baseline (15.018 us; speedup 1.0000x reference)
//
#include <hip/hip_runtime.h>
#include <math.h>

#define WINDOW_MAX 256
#define NEG -1000000.0f

typedef __attribute__((address_space(1))) const float gfloat;
typedef __attribute__((address_space(3))) float lfloat;

#define WS_STRIDE 132   // per-(bh,half) slot: 128 partial-out + 1 partial-sum

// ---------------- kernel 1: half-window partial attention ----------------
// grid (H, B, 2), 512 threads. Each block handles 128 of the 256 window rows
// for one (b,h). Everything after exp is linear, so the block emits:
//   pout[e] = sum_{s in half} p_s * x_s . Wv[:,e]   (unnormalized)
//   psum    = sum_{s in half} p_s
// Kernel 2 combines: out = (pout0+pout1)/(psum0+psum1) + bv + content.
// Per-block LDS ~81 KB; 256 blocks = 1/CU on all 256 CUs (was 128 CUs).
// xs layout: 128 floats/row, 16B-chunk XOR swizzle (lds chunk c = f ^ (row&7)).
__global__ __launch_bounds__(512, 2) void bca_half(
    const float* __restrict__ content,   // (B, D)
    const float* __restrict__ cache,     // (B, T, D)
    const float* __restrict__ Wq,        // (H, 128, 128)
    const float* __restrict__ bq,        // (H, 128)
    const float* __restrict__ Wk,        // (H, 128, 128)
    const float* __restrict__ Wv,        // (H, 128, 128)
    const float* __restrict__ pos_param_p,
    float* __restrict__ wsp,             // workspace partials
    int B, int T, int D, int H, int S, int cutoff)
{
    constexpr int HD = 128;
    constexpr int NR = 128;              // rows per block (half window)

    __shared__ float xs[NR * HD];        // 65536 B, swizzled 16B chunks
    __shared__ float qp[2][HD];          // q partials
    __shared__ float kp[2][HD];          // qk partials
    __shared__ float kfull[HD];          // kp[0]+kp[1]
    __shared__ float scp[4][NR];         // score partials (4 d-quarters)
    __shared__ float sc[NR];             // unnormalized p
    __shared__ float wp[16][HD];         // PV partials (16 s-groups)
    __shared__ float wsum_s[HD];         // partial weighted sum
    __shared__ float op[4][HD];          // out-matvec quarter partials
    __shared__ float red2[2];            // p-sum partials

    const int tid  = threadIdx.x;
    const int h    = blockIdx.x, b = blockIdx.y, half = blockIdx.z;
    const float* cnt_g = content + (size_t)b * D + h * HD;
    const float* cb    = cache + (size_t)b * T * D + h * HD;

    const float pos_param = pos_param_p[0];
    const int e128 = tid & 127;
    const int g4   = tid >> 7;                         // 0..3, wave-uniform
    const int d4   = tid & 31;                         // PV: float4 chunk id
    const int sg   = tid >> 5;                         // PV: s-group 0..15
    const int base = half * NR;                        // global row offset

    float wvreg[32];                     // Wv[g4*32+i][e128], loaded post-B2

    if (tid < 256) {
        // ===== C-waves 0-3: Wk->regs, q matvec, qk =====
        const int g2 = g4;                             // 0/1
        float4 wk4[16];
        {
            const float* wkp = Wk + h * HD * HD + e128 * HD + g2 * 64;
            #pragma unroll
            for (int j = 0; j < 16; ++j) wk4[j] = *(const float4*)(wkp + j * 4);
        }
        const float* wqp = Wq + h * HD * HD + (g2 * 64) * HD + e128;
        const float* cg  = cnt_g + g2 * 64;            // wave-uniform reads
        float acc = (g2 == 0) ? bq[h * HD + e128] : 0.f;
        #pragma unroll
        for (int i = 0; i < 64; ++i)
            acc = fmaf(cg[i], wqp[i * HD], acc);
        qp[g2][e128] = acc;

        __syncthreads();   // B1: q partials + window staged

        float a2 = 0.f;
        #pragma unroll
        for (int j = 0; j < 16; ++j) {
            const float4 q0 = *(const float4*)&qp[0][g2 * 64 + j * 4]; // broadcast
            const float4 q1 = *(const float4*)&qp[1][g2 * 64 + j * 4];
            a2 = fmaf(wk4[j].x, q0.x + q1.x, a2);
            a2 = fmaf(wk4[j].y, q0.y + q1.y, a2);
            a2 = fmaf(wk4[j].z, q0.z + q1.z, a2);
            a2 = fmaf(wk4[j].w, q0.w + q1.w, a2);
        }
        kp[g2][e128] = a2;
    } else {
        // ===== S-waves 4-7: stage 128 rows (32/wave, 16 gload_lds each) =====
        const int sw   = (tid >> 6) - 4;               // 0..3
        const int lane = tid & 63;
        #pragma unroll
        for (int i = 0; i < 16; ++i) {
            const int w    = sw * 32 + i * 2;          // local row pair
            const int row  = w + (lane >> 5);          // local row 0..127
            const int f    = (lane & 31) ^ (row & 7);
            const int gpos = cutoff + base + row;
            const float* src = (gpos < T) ? (cb + (size_t)gpos * D + f * 4)
                                          : (cnt_g + f * 4);
            __builtin_amdgcn_global_load_lds((gfloat*)src, (lfloat*)&xs[w << 7],
                                             16, 0, 0);
        }
        __syncthreads();   // B1 (drains vmcnt -> xs complete)
    }
    __syncthreads();       // B2: kp ready

    // ---- all waves: Wv quarter; lands under scores/softmax ----
    {
        const float* wvp = Wv + h * HD * HD + (g4 * 32) * HD + e128;
        #pragma unroll
        for (int i = 0; i < 32; ++i) wvreg[i] = wvp[i * HD];
    }

    if (tid < HD) kfull[tid] = kp[0][tid] + kp[1][tid];
    __syncthreads();   // B2b

    // ---- scores: 512 thr = 128 s x 4 d-quarters ----
    {
        const int s = tid & 127, dq = tid >> 7;        // dq wave-uniform
        const int swz = s & 7;
        float acc = 0.f;
        #pragma unroll
        for (int j = 0; j < 8; ++j) {
            const int c = (dq * 8 + j) ^ swz;
            const float4 x  = *(const float4*)&xs[(s << 7) + (c << 2)];
            const float4 kf = *(const float4*)&kfull[dq * 32 + j * 4]; // broadcast
            acc = fmaf(x.x, kf.x, acc);
            acc = fmaf(x.y, kf.y, acc);
            acc = fmaf(x.z, kf.z, acc);
            acc = fmaf(x.w, kf.w, acc);
        }
        scp[dq][s] = acc;
    }
    __syncthreads();   // B3

    // ---- softmax weights (no max; subtract constant NEG — exact) ----
    float p = 0.f;
    if (tid < NR) {
        const float dot = scp[0][tid] + scp[1][tid] + scp[2][tid] + scp[3][tid];
        const int n = (WINDOW_MAX - 1) - (base + tid); // distance to query
        float posb;
        if (n < 16) {
            posb = (float)n;
        } else {
            const float lc = 2.0794415416798357f;      // float32(log(8))
            int large = 16 + (int)((logf((float)n / 16.0f) / lc) * 16.0f);
            if (large > 31) large = 31;
            posb = (float)large;
        }
        // time_mask collapses to NEG everywhere; +NEG reproduces the ref's
        // pre-softmax quantization; (y+NEG)-NEG exact; factor cancels in 1/SUM.
        const float score = (dot / 11.313708498984761f) - pos_param * posb + NEG;
        p = expf(score - NEG);
        sc[tid] = p;
    }
    float ssum = p;
    #pragma unroll
    for (int off = 32; off >= 1; off >>= 1) ssum += __shfl_xor(ssum, off);
    if (tid < NR && (tid & 63) == 0) red2[tid >> 6] = ssum;
    __syncthreads();   // B5: sc + red2 ready

    // ---- PV partials: 32 d-chunks x 16 s-groups, 8 rows each, b128 ----
    {
        float4 wacc = make_float4(0.f, 0.f, 0.f, 0.f);
        #pragma unroll
        for (int ii = 0; ii < 2; ++ii) {
            const float4 ps = *(const float4*)&sc[sg * 8 + ii * 4];  // broadcast
            const float pw[4] = { ps.x, ps.y, ps.z, ps.w };
            #pragma unroll
            for (int k = 0; k < 4; ++k) {
                const int r = sg * 8 + ii * 4 + k;
                const int c = d4 ^ (r & 7);
                const float4 x = *(const float4*)&xs[(r << 7) + (c << 2)];
                wacc.x = fmaf(pw[k], x.x, wacc.x);
                wacc.y = fmaf(pw[k], x.y, wacc.y);
                wacc.z = fmaf(pw[k], x.z, wacc.z);
                wacc.w = fmaf(pw[k], x.w, wacc.w);
            }
        }
        *(float4*)&wp[sg][d4 << 2] = wacc;
    }
    __syncthreads();   // B6

    if (tid < HD) {
        float t = 0.f;
        #pragma unroll
        for (int s2 = 0; s2 < 16; ++s2) t += wp[s2][tid];
        wsum_s[tid] = t;
    }
    __syncthreads();   // B6b

    // ---- out quarter: op[g4][e] = sum_{i<32} wsum[g4*32+i]*Wv[g4*32+i][e] ----
    {
        float acc = 0.f;
        #pragma unroll
        for (int i = 0; i < 32; ++i)
            acc = fmaf(wsum_s[g4 * 32 + i], wvreg[i], acc);
        op[g4][e128] = acc;
    }
    __syncthreads();   // B7

    // ---- emit partials ----
    float* slot = wsp + ((size_t)(b * H + h) * 2 + half) * WS_STRIDE;
    if (tid < HD)
        slot[tid] = op[0][tid] + op[1][tid] + op[2][tid] + op[3][tid];
    if (tid == 0)
        slot[HD] = red2[0] + red2[1];
}

// ---------------- kernel 2: combine halves ----------------
__global__ __launch_bounds__(256) void bca_combine(
    const float* __restrict__ wsp,
    const float* __restrict__ content,   // (B, D)
    const float* __restrict__ bv,        // (H, 128)
    float* __restrict__ out,             // (B, D)
    int H, int total)                    // total = B*H*128
{
    const int idx = blockIdx.x * 256 + threadIdx.x;
    if (idx >= total) return;
    const int bh = idx >> 7, e = idx & 127;
    const float* s0 = wsp + ((size_t)bh * 2 + 0) * WS_STRIDE;
    const float* s1 = wsp + ((size_t)bh * 2 + 1) * WS_STRIDE;
    const float SUM = s0[128] + s1[128];
    const float r = (s0[e] + s1[e]) * (1.0f / SUM)
                  + bv[(bh % H) * 128 + e] + content[idx];
    out[idx] = r;
}

// ---------------- generic fallback (any window<=256) ----------
__global__ __launch_bounds__(256) void bca_generic(
    const float* __restrict__ content, const float* __restrict__ cache,
    const float* __restrict__ Wq, const float* __restrict__ bq,
    const float* __restrict__ Wk, const float* __restrict__ Wv,
    const float* __restrict__ bv, const float* __restrict__ pos_param_p,
    float* __restrict__ out,
    int B, int T, int D, int H, int S, int window, int cutoff)
{
    constexpr int HD = 128;
    constexpr int XP = HD + 1;
    const int bh = blockIdx.x;
    const int b = bh / H, h = bh % H;
    const int tid = threadIdx.x;

    __shared__ float xs[WINDOW_MAX * XP];
    __shared__ float cnt_s[HD];
    __shared__ float q_s[HD];
    __shared__ float qk_s[HD];
    __shared__ float sc_s[WINDOW_MAX];
    __shared__ float part_s[256];
    __shared__ float wsum_s[HD];
    __shared__ float red_s[4];

    const float* cnt_g = content + (size_t)b * D + (size_t)h * HD;
    if (tid < HD) cnt_s[tid] = cnt_g[tid];

    const int total4 = window * (HD / 4);
    for (int idx = tid; idx < total4; idx += blockDim.x) {
        const int w = idx >> 5, f = idx & 31;
        const int gpos = cutoff + w;
        const float* src = (gpos < T)
            ? (cache + (size_t)b * T * D + (size_t)gpos * D + (size_t)h * HD)
            : cnt_g;
        const float4 v4 = *(const float4*)(src + f * 4);
        float* dst = &xs[w * XP + f * 4];
        dst[0] = v4.x; dst[1] = v4.y; dst[2] = v4.z; dst[3] = v4.w;
    }
    __syncthreads();

    if (tid < HD) {
        const float* wq = Wq + (size_t)h * HD * HD;
        float acc = 0.f;
        #pragma unroll 8
        for (int d = 0; d < HD; ++d) acc = fmaf(cnt_s[d], wq[d * HD + tid], acc);
        q_s[tid] = acc + bq[h * HD + tid];
    }
    __syncthreads();

    if (tid < HD) {
        const float* wk = Wk + (size_t)h * HD * HD + (size_t)tid * HD;
        float acc = 0.f;
        #pragma unroll 8
        for (int e = 0; e < HD; e += 4) {
            const float4 w4 = *(const float4*)(wk + e);
            acc = fmaf(w4.x, q_s[e],     acc);
            acc = fmaf(w4.y, q_s[e + 1], acc);
            acc = fmaf(w4.z, q_s[e + 2], acc);
            acc = fmaf(w4.w, q_s[e + 3], acc);
        }
        qk_s[tid] = acc;
    }
    __syncthreads();

    const float pos_param = pos_param_p[0];
    float score = -INFINITY;
    if (tid < window) {
        float acc = 0.f;
        const float* xr = &xs[tid * XP];
        #pragma unroll 8
        for (int d = 0; d < HD; ++d) acc = fmaf(qk_s[d], xr[d], acc);
        const int gpos = cutoff + tid;
        const int n = (S - 1) - gpos;
        float posb;
        if (n < 16) posb = (float)n;
        else {
            const float lc = 2.0794415416798357f;
            int large = 16 + (int)((logf((float)n / 16.0f) / lc) * 16.0f);
            if (large > 31) large = 31;
            posb = (float)large;
        }
        score = (acc / 11.313708498984761f) - pos_param * posb + NEG;
    }

    float m = score;
    #pragma unroll
    for (int off = 32; off >= 1; off >>= 1) m = fmaxf(m, __shfl_xor(m, off));
    if ((tid & 63) == 0) red_s[tid >> 6] = m;
    __syncthreads();
    const int nw = blockDim.x >> 6;
    float M = red_s[0];
    for (int i = 1; i < nw; ++i) M = fmaxf(M, red_s[i]);

    float p = (tid < window) ? expf(score - M) : 0.f;
    float ssum = p;
    #pragma unroll
    for (int off = 32; off >= 1; off >>= 1) ssum += __shfl_xor(ssum, off);
    __syncthreads();
    if ((tid & 63) == 0) red_s[tid >> 6] = ssum;
    __syncthreads();
    float SUM = 0.f;
    for (int i = 0; i < nw; ++i) SUM += red_s[i];
    const float inv = 1.0f / SUM;
    if (tid < window) sc_s[tid] = p * inv;
    __syncthreads();

    {
        const int d = tid & (HD - 1), half = tid >> 7;
        const int s0 = half * (window >> 1), s1 = s0 + (window >> 1);
        float acc = 0.f;
        for (int s = s0; s < s1; ++s) acc = fmaf(sc_s[s], xs[s * XP + d], acc);
        part_s[tid] = acc;
    }
    __syncthreads();
    if (tid < HD) wsum_s[tid] = part_s[tid] + part_s[tid + HD];
    __syncthreads();

    {
        const int e = tid & (HD - 1), dh = tid >> 7;
        const float* wv = Wv + (size_t)h * HD * HD;
        float acc = 0.f;
        for (int d = dh * 64; d < dh * 64 + 64; ++d)
            acc = fmaf(wsum_s[d], wv[d * HD + e], acc);
        part_s[tid] = acc;
    }
    __syncthreads();
    if (tid < HD) {
        const float r = part_s[tid] + part_s[tid + HD]
                      + bv[h * HD + tid] + cnt_g[tid];
        out[(size_t)b * D + (size_t)h * HD + tid] = r;
    }
}

extern "C" void kernel_launch(void* const* d_in, const int* in_sizes, int n_in,
                              void* d_out, int out_size, void* d_ws, size_t ws_size,
                              hipStream_t stream) {
    // inputs: 0:t 1:content_t 2:time_mask 3:cache 4:speakers 5:Wq 6:bq 7:Wk 8:bk 9:Wv 10:bv 11:pos_param
    const float* content = (const float*)d_in[1];
    const float* cache   = (const float*)d_in[3];
    const float* Wq      = (const float*)d_in[5];
    const float* bq      = (const float*)d_in[6];
    const float* Wk      = (const float*)d_in[7];
    const float* Wv      = (const float*)d_in[9];
    const float* bv      = (const float*)d_in[10];
    const float* posp    = (const float*)d_in[11];

    const int D  = in_sizes[6];
    const int B  = in_sizes[1] / D;
    const int hd = in_sizes[5] / D;
    const int H  = D / hd;
    const int T  = in_sizes[3] / (B * D);
    const int S  = T + 1;
    const int window = (S < WINDOW_MAX) ? S : WINDOW_MAX;
    const int cutoff = S - window;

    if (window == WINDOW_MAX && hd == 128) {
        float* wsp = (float*)d_ws;       // B*H*2*132 floats ~ 135 KB << ws_size
        dim3 grid1(H, B, 2), block1(512);
        hipLaunchKernelGGL(bca_half, grid1, block1, 0, stream,
                           content, cache, Wq, bq, Wk, Wv, posp,
                           wsp, B, T, D, H, S, cutoff);
        const int total = B * H * 128;
        dim3 grid2((total + 255) / 256), block2(256);
        hipLaunchKernelGGL(bca_combine, grid2, block2, 0, stream,
                           wsp, content, bv, (float*)d_out, H, total);
    } else {
        dim3 grid(B * H), block(256);
        hipLaunchKernelGGL(bca_generic, grid, block, 0, stream,
                           content, cache, Wq, bq, Wk, Wv, bv, posp,
                           (float*)d_out, B, T, D, H, S, window, cutoff);
    }
}

// Round 12
// 14.978 us; speedup vs baseline: 1.0027x; 1.0027x over previous
//
#include <hip/hip_runtime.h>
#include <math.h>

#define WINDOW_MAX 256
#define NEG -1000000.0f
#define MAGIC 0x5AC0FFEE
#define WS_STRIDE 132   // per-(bh,half) slot: 128 partial-out + 1 partial-sum

typedef __attribute__((address_space(1))) const float gfloat;
typedef __attribute__((address_space(3))) float lfloat;

// ---------------- fast path: half-window blocks + in-kernel combine ----------
// grid (H, B, 2), 512 threads; 256 blocks = 1/CU on all 256 CUs.
// Each block: stage 128 rows (64KB) -> half scores -> exp -> half PV -> half
// out-matvec -> emit (pout, psum) partials via DEVICE-SCOPE atomics to ws.
// Combine-by-second-arriver: tid0 sets flag=MAGIC, bounded-polls partner flag;
// any block that sees partner's MAGIC does the idempotent combine
//   out = (pout0+pout1)/(psum0+psum1) + bv + content
// and resets both flags to 0 (self-restoring across graph replays; robust to
// 0xAA-poisoned initial flags since poison != MAGIC). No spin-deadlock: polls
// are bounded and a timeout block simply exits (partner combines later).
// At-least-one-combiner: flag atomics serialize at one coherence point, so the
// later writer's first poll sees the earlier MAGIC (unless already combined).
__global__ __launch_bounds__(512, 2) void bca_half(
    const float* __restrict__ content,   // (B, D)
    const float* __restrict__ cache,     // (B, T, D)
    const float* __restrict__ Wq,        // (H, 128, 128)
    const float* __restrict__ bq,        // (H, 128)
    const float* __restrict__ Wk,        // (H, 128, 128)
    const float* __restrict__ Wv,        // (H, 128, 128)
    const float* __restrict__ bv,        // (H, 128)
    const float* __restrict__ pos_param_p,
    float* __restrict__ wsp,             // partial slots
    int* __restrict__ flags,             // 2 per (b,h)
    float* __restrict__ out,             // (B, D)
    int B, int T, int D, int H, int S, int cutoff)
{
    constexpr int HD = 128;
    constexpr int NR = 128;              // rows per block (half window)

    __shared__ float xs[NR * HD];        // 65536 B, swizzled 16B chunks
    __shared__ float qp[2][HD];
    __shared__ float kp[2][HD];
    __shared__ float kfull[HD];
    __shared__ float scp[4][NR];
    __shared__ float sc[NR];
    __shared__ float wp[16][HD];
    __shared__ float wsum_s[HD];
    __shared__ float op[4][HD];
    __shared__ float red2[2];
    __shared__ float thSum_s;
    __shared__ int   doC;

    const int tid  = threadIdx.x;
    const int h    = blockIdx.x, b = blockIdx.y, half = blockIdx.z;
    const float* cnt_g = content + (size_t)b * D + h * HD;
    const float* cb    = cache + (size_t)b * T * D + h * HD;

    const float pos_param = pos_param_p[0];
    const int e128 = tid & 127;
    const int g4   = tid >> 7;                         // 0..3, wave-uniform
    const int d4   = tid & 31;
    const int sg   = tid >> 5;
    const int base = half * NR;

    float creg = 0.f, bvreg = 0.f;
    if (tid < HD) { creg = cnt_g[tid]; bvreg = bv[h * HD + tid]; }

    float wvreg[32];

    if (tid < 256) {
        // ===== C-waves 0-3: Wk->regs, q matvec, qk =====
        const int g2 = g4;                             // 0/1
        float4 wk4[16];
        {
            const float* wkp = Wk + h * HD * HD + e128 * HD + g2 * 64;
            #pragma unroll
            for (int j = 0; j < 16; ++j) wk4[j] = *(const float4*)(wkp + j * 4);
        }
        const float* wqp = Wq + h * HD * HD + (g2 * 64) * HD + e128;
        const float* cg  = cnt_g + g2 * 64;            // wave-uniform reads
        float acc = (g2 == 0) ? bq[h * HD + e128] : 0.f;
        #pragma unroll
        for (int i = 0; i < 64; ++i)
            acc = fmaf(cg[i], wqp[i * HD], acc);
        qp[g2][e128] = acc;

        __syncthreads();   // B1

        float a2 = 0.f;
        #pragma unroll
        for (int j = 0; j < 16; ++j) {
            const float4 q0 = *(const float4*)&qp[0][g2 * 64 + j * 4];
            const float4 q1 = *(const float4*)&qp[1][g2 * 64 + j * 4];
            a2 = fmaf(wk4[j].x, q0.x + q1.x, a2);
            a2 = fmaf(wk4[j].y, q0.y + q1.y, a2);
            a2 = fmaf(wk4[j].z, q0.z + q1.z, a2);
            a2 = fmaf(wk4[j].w, q0.w + q1.w, a2);
        }
        kp[g2][e128] = a2;
    } else {
        // ===== S-waves 4-7: stage 128 rows (32/wave, 16 gload_lds each) =====
        const int sw   = (tid >> 6) - 4;
        const int lane = tid & 63;
        #pragma unroll
        for (int i = 0; i < 16; ++i) {
            const int w    = sw * 32 + i * 2;
            const int row  = w + (lane >> 5);
            const int f    = (lane & 31) ^ (row & 7);
            const int gpos = cutoff + base + row;
            const float* src = (gpos < T) ? (cb + (size_t)gpos * D + f * 4)
                                          : (cnt_g + f * 4);
            __builtin_amdgcn_global_load_lds((gfloat*)src, (lfloat*)&xs[w << 7],
                                             16, 0, 0);
        }
        __syncthreads();   // B1
    }
    __syncthreads();       // B2: kp ready

    // ---- Wv quarter; lands under scores/softmax ----
    {
        const float* wvp = Wv + h * HD * HD + (g4 * 32) * HD + e128;
        #pragma unroll
        for (int i = 0; i < 32; ++i) wvreg[i] = wvp[i * HD];
    }

    if (tid < HD) kfull[tid] = kp[0][tid] + kp[1][tid];
    __syncthreads();   // B2b

    // ---- scores: 512 thr = 128 s x 4 d-quarters ----
    {
        const int s = tid & 127, dq = tid >> 7;
        const int swz = s & 7;
        float acc = 0.f;
        #pragma unroll
        for (int j = 0; j < 8; ++j) {
            const int c = (dq * 8 + j) ^ swz;
            const float4 x  = *(const float4*)&xs[(s << 7) + (c << 2)];
            const float4 kf = *(const float4*)&kfull[dq * 32 + j * 4];
            acc = fmaf(x.x, kf.x, acc);
            acc = fmaf(x.y, kf.y, acc);
            acc = fmaf(x.z, kf.z, acc);
            acc = fmaf(x.w, kf.w, acc);
        }
        scp[dq][s] = acc;
    }
    __syncthreads();   // B3

    // ---- softmax weights (no max; subtract constant NEG — exact) ----
    float p = 0.f;
    if (tid < NR) {
        const float dot = scp[0][tid] + scp[1][tid] + scp[2][tid] + scp[3][tid];
        const int n = (WINDOW_MAX - 1) - (base + tid);
        float posb;
        if (n < 16) {
            posb = (float)n;
        } else {
            const float lc = 2.0794415416798357f;      // float32(log(8))
            int large = 16 + (int)((logf((float)n / 16.0f) / lc) * 16.0f);
            if (large > 31) large = 31;
            posb = (float)large;
        }
        // time_mask collapses to NEG everywhere; +NEG reproduces the ref's
        // pre-softmax quantization; (y+NEG)-NEG exact; factor cancels in 1/SUM.
        const float score = (dot / 11.313708498984761f) - pos_param * posb + NEG;
        p = expf(score - NEG);
        sc[tid] = p;
    }
    float ssum = p;
    #pragma unroll
    for (int off = 32; off >= 1; off >>= 1) ssum += __shfl_xor(ssum, off);
    if (tid < NR && (tid & 63) == 0) red2[tid >> 6] = ssum;
    __syncthreads();   // B5

    // ---- PV partials: 32 d-chunks x 16 s-groups, 8 rows each, b128 ----
    {
        float4 wacc = make_float4(0.f, 0.f, 0.f, 0.f);
        #pragma unroll
        for (int ii = 0; ii < 2; ++ii) {
            const float4 ps = *(const float4*)&sc[sg * 8 + ii * 4];
            const float pw[4] = { ps.x, ps.y, ps.z, ps.w };
            #pragma unroll
            for (int k = 0; k < 4; ++k) {
                const int r = sg * 8 + ii * 4 + k;
                const int c = d4 ^ (r & 7);
                const float4 x = *(const float4*)&xs[(r << 7) + (c << 2)];
                wacc.x = fmaf(pw[k], x.x, wacc.x);
                wacc.y = fmaf(pw[k], x.y, wacc.y);
                wacc.z = fmaf(pw[k], x.z, wacc.z);
                wacc.w = fmaf(pw[k], x.w, wacc.w);
            }
        }
        *(float4*)&wp[sg][d4 << 2] = wacc;
    }
    __syncthreads();   // B6

    if (tid < HD) {
        float t = 0.f;
        #pragma unroll
        for (int s2 = 0; s2 < 16; ++s2) t += wp[s2][tid];
        wsum_s[tid] = t;
    }
    __syncthreads();   // B6b

    {
        float acc = 0.f;
        #pragma unroll
        for (int i = 0; i < 32; ++i)
            acc = fmaf(wsum_s[g4 * 32 + i], wvreg[i], acc);
        op[g4][e128] = acc;
    }
    __syncthreads();   // B7: op + red2 final

    // ---- emit partials (device-scope atomics: G16-safe cross-XCD) ----
    const int bh = b * H + h;
    float* mySlot = wsp + ((size_t)bh * 2 + half) * WS_STRIDE;
    float* thSlot = wsp + ((size_t)bh * 2 + (1 - half)) * WS_STRIDE;
    int* fMine    = flags + bh * 2 + half;
    int* fTheirs  = flags + bh * 2 + (1 - half);

    const float mySum = red2[0] + red2[1];
    float myPart = 0.f;
    if (tid < HD) {
        myPart = op[0][tid] + op[1][tid] + op[2][tid] + op[3][tid];
        atomicExch(&mySlot[tid], myPart);
    }
    if (tid == HD) atomicExch(&mySlot[HD], mySum);
    __syncthreads();   // B8: partial atomics complete (vmcnt drained)

    if (tid == 0) {
        atomicExch(fMine, MAGIC);
        int seen = 0;
        #pragma unroll 1
        for (int it = 0; it < 256 && !seen; ++it) {
            seen = (atomicOr(fTheirs, 0) == MAGIC);
            if (!seen) __builtin_amdgcn_s_sleep(1);
        }
        doC = seen;
        if (seen) {            // I combine -> reset both flags for next replay
            atomicExch(fMine, 0);
            atomicExch(fTheirs, 0);
        }
    }
    __syncthreads();   // B9

    if (doC) {
        float thPart = 0.f;
        if (tid < HD)  thPart = atomicAdd(&thSlot[tid], 0.0f);   // atomic read
        if (tid == HD) thSum_s = atomicAdd(&thSlot[HD], 0.0f);
        __syncthreads();   // B10
        if (tid < HD) {
            const float SUM = mySum + thSum_s;
            out[(size_t)b * D + h * HD + tid] =
                (myPart + thPart) * (1.0f / SUM) + bvreg + creg;
        }
    }
}

// ---------------- generic fallback (any window<=256) ----------
__global__ __launch_bounds__(256) void bca_generic(
    const float* __restrict__ content, const float* __restrict__ cache,
    const float* __restrict__ Wq, const float* __restrict__ bq,
    const float* __restrict__ Wk, const float* __restrict__ Wv,
    const float* __restrict__ bv, const float* __restrict__ pos_param_p,
    float* __restrict__ out,
    int B, int T, int D, int H, int S, int window, int cutoff)
{
    constexpr int HD = 128;
    constexpr int XP = HD + 1;
    const int bh = blockIdx.x;
    const int b = bh / H, h = bh % H;
    const int tid = threadIdx.x;

    __shared__ float xs[WINDOW_MAX * XP];
    __shared__ float cnt_s[HD];
    __shared__ float q_s[HD];
    __shared__ float qk_s[HD];
    __shared__ float sc_s[WINDOW_MAX];
    __shared__ float part_s[256];
    __shared__ float wsum_s[HD];
    __shared__ float red_s[4];

    const float* cnt_g = content + (size_t)b * D + (size_t)h * HD;
    if (tid < HD) cnt_s[tid] = cnt_g[tid];

    const int total4 = window * (HD / 4);
    for (int idx = tid; idx < total4; idx += blockDim.x) {
        const int w = idx >> 5, f = idx & 31;
        const int gpos = cutoff + w;
        const float* src = (gpos < T)
            ? (cache + (size_t)b * T * D + (size_t)gpos * D + (size_t)h * HD)
            : cnt_g;
        const float4 v4 = *(const float4*)(src + f * 4);
        float* dst = &xs[w * XP + f * 4];
        dst[0] = v4.x; dst[1] = v4.y; dst[2] = v4.z; dst[3] = v4.w;
    }
    __syncthreads();

    if (tid < HD) {
        const float* wq = Wq + (size_t)h * HD * HD;
        float acc = 0.f;
        #pragma unroll 8
        for (int d = 0; d < HD; ++d) acc = fmaf(cnt_s[d], wq[d * HD + tid], acc);
        q_s[tid] = acc + bq[h * HD + tid];
    }
    __syncthreads();

    if (tid < HD) {
        const float* wk = Wk + (size_t)h * HD * HD + (size_t)tid * HD;
        float acc = 0.f;
        #pragma unroll 8
        for (int e = 0; e < HD; e += 4) {
            const float4 w4 = *(const float4*)(wk + e);
            acc = fmaf(w4.x, q_s[e],     acc);
            acc = fmaf(w4.y, q_s[e + 1], acc);
            acc = fmaf(w4.z, q_s[e + 2], acc);
            acc = fmaf(w4.w, q_s[e + 3], acc);
        }
        qk_s[tid] = acc;
    }
    __syncthreads();

    const float pos_param = pos_param_p[0];
    float score = -INFINITY;
    if (tid < window) {
        float acc = 0.f;
        const float* xr = &xs[tid * XP];
        #pragma unroll 8
        for (int d = 0; d < HD; ++d) acc = fmaf(qk_s[d], xr[d], acc);
        const int gpos = cutoff + tid;
        const int n = (S - 1) - gpos;
        float posb;
        if (n < 16) posb = (float)n;
        else {
            const float lc = 2.0794415416798357f;
            int large = 16 + (int)((logf((float)n / 16.0f) / lc) * 16.0f);
            if (large > 31) large = 31;
            posb = (float)large;
        }
        score = (acc / 11.313708498984761f) - pos_param * posb + NEG;
    }

    float m = score;
    #pragma unroll
    for (int off = 32; off >= 1; off >>= 1) m = fmaxf(m, __shfl_xor(m, off));
    if ((tid & 63) == 0) red_s[tid >> 6] = m;
    __syncthreads();
    const int nw = blockDim.x >> 6;
    float M = red_s[0];
    for (int i = 1; i < nw; ++i) M = fmaxf(M, red_s[i]);

    float p = (tid < window) ? expf(score - M) : 0.f;
    float ssum = p;
    #pragma unroll
    for (int off = 32; off >= 1; off >>= 1) ssum += __shfl_xor(ssum, off);
    __syncthreads();
    if ((tid & 63) == 0) red_s[tid >> 6] = ssum;
    __syncthreads();
    float SUM = 0.f;
    for (int i = 0; i < nw; ++i) SUM += red_s[i];
    const float inv = 1.0f / SUM;
    if (tid < window) sc_s[tid] = p * inv;
    __syncthreads();

    {
        const int d = tid & (HD - 1), half = tid >> 7;
        const int s0 = half * (window >> 1), s1 = s0 + (window >> 1);
        float acc = 0.f;
        for (int s = s0; s < s1; ++s) acc = fmaf(sc_s[s], xs[s * XP + d], acc);
        part_s[tid] = acc;
    }
    __syncthreads();
    if (tid < HD) wsum_s[tid] = part_s[tid] + part_s[tid + HD];
    __syncthreads();

    {
        const int e = tid & (HD - 1), dh = tid >> 7;
        const float* wv = Wv + (size_t)h * HD * HD;
        float acc = 0.f;
        for (int d = dh * 64; d < dh * 64 + 64; ++d)
            acc = fmaf(wsum_s[d], wv[d * HD + e], acc);
        part_s[tid] = acc;
    }
    __syncthreads();
    if (tid < HD) {
        const float r = part_s[tid] + part_s[tid + HD]
                      + bv[h * HD + tid] + cnt_g[tid];
        out[(size_t)b * D + (size_t)h * HD + tid] = r;
    }
}

extern "C" void kernel_launch(void* const* d_in, const int* in_sizes, int n_in,
                              void* d_out, int out_size, void* d_ws, size_t ws_size,
                              hipStream_t stream) {
    // inputs: 0:t 1:content_t 2:time_mask 3:cache 4:speakers 5:Wq 6:bq 7:Wk 8:bk 9:Wv 10:bv 11:pos_param
    const float* content = (const float*)d_in[1];
    const float* cache   = (const float*)d_in[3];
    const float* Wq      = (const float*)d_in[5];
    const float* bq      = (const float*)d_in[6];
    const float* Wk      = (const float*)d_in[7];
    const float* Wv      = (const float*)d_in[9];
    const float* bv      = (const float*)d_in[10];
    const float* posp    = (const float*)d_in[11];

    const int D  = in_sizes[6];
    const int B  = in_sizes[1] / D;
    const int hd = in_sizes[5] / D;
    const int H  = D / hd;
    const int T  = in_sizes[3] / (B * D);
    const int S  = T + 1;
    const int window = (S < WINDOW_MAX) ? S : WINDOW_MAX;
    const int cutoff = S - window;

    if (window == WINDOW_MAX && hd == 128) {
        float* wsp = (float*)d_ws;                       // B*H*2*132 floats
        int*   flags = (int*)(wsp + (size_t)B * H * 2 * WS_STRIDE);
        dim3 grid1(H, B, 2), block1(512);
        hipLaunchKernelGGL(bca_half, grid1, block1, 0, stream,
                           content, cache, Wq, bq, Wk, Wv, bv, posp,
                           wsp, flags, (float*)d_out, B, T, D, H, S, cutoff);
    } else {
        dim3 grid(B * H), block(256);
        hipLaunchKernelGGL(bca_generic, grid, block, 0, stream,
                           content, cache, Wq, bq, Wk, Wv, bv, posp,
                           (float*)d_out, B, T, D, H, S, window, cutoff);
    }
}

// Round 13
// 14.517 us; speedup vs baseline: 1.0345x; 1.0317x over previous
//
#include <hip/hip_runtime.h>
#include <math.h>

#define WINDOW_MAX 256
#define NEG -1000000.0f

typedef __attribute__((address_space(1))) const float gfloat;
typedef __attribute__((address_space(3))) float lfloat;

// ---------------- fast path: window==256, hd==128, 512 threads ----------------
// One block per (b,h): grid (H, B) -> same-h blocks share an XCD L2 for weights.
// R12 = R9 restored verbatim (best measured: 14.29 us). R10 (split + combine
// kernel) and R11 (split + in-kernel atomic combine) both regressed; the
// session floor is F (~7-8us fixed replay overhead) + ~3us mandatory HBM
// fetch (L3 evicted by per-replay 512MB ws fills) + ~3us serial phase chain.
//   - no-max softmax: p = exp(score - NEG) (exact; constant cancels in 1/SUM)
//   - Wv prefetch issued AFTER B2 on all waves (quarter each), landing under
//     the scores phase; out matvec is 4-way.
//   - kfull[d] = kp[0][d]+kp[1][d] precomputed once -> scores does 2
//     ds_read_b128 per j instead of 3.
//   - PV: 512 thr = 32 d-chunks x 16 s-groups, float4 accumulation, b128 LDS.
// Waves 0-3 (C): Wk->regs, q matvec (Wq streamed), qk. Waves 4-7 (S): window
// via 32x async global_load_lds.
// xs layout: 128 floats/row, 16B-chunk XOR swizzle (lds chunk c = f ^ (row&7)).
__global__ __launch_bounds__(512, 2) void bca_fast(
    const float* __restrict__ content,   // (B, D)
    const float* __restrict__ cache,     // (B, T, D)
    const float* __restrict__ Wq,        // (H, 128, 128)
    const float* __restrict__ bq,        // (H, 128)
    const float* __restrict__ Wk,        // (H, 128, 128)
    const float* __restrict__ Wv,        // (H, 128, 128)
    const float* __restrict__ bv,        // (H, 128)
    const float* __restrict__ pos_param_p,
    float* __restrict__ out,             // (B, D)
    int B, int T, int D, int H, int S, int cutoff)
{
    constexpr int HD  = 128;
    constexpr int WIN = 256;

    __shared__ float xs[WIN * HD];       // 131072 B, swizzled 16B chunks
    __shared__ float qp[2][HD];          // q partials (g2=0 half includes bq)
    __shared__ float kp[2][HD];          // qk partials
    __shared__ float kfull[HD];          // kp[0]+kp[1]
    __shared__ float scp[2][WIN];        // score partials
    __shared__ float sc[WIN];            // UNNORMALIZED softmax weights p
    __shared__ float wp[16][HD];         // PV partials (16 s-groups)
    __shared__ float ws[HD];             // unnormalized weighted sum
    __shared__ float op[4][HD];          // output quarter partials
    __shared__ float red2[8];            // p-sum partials

    const int tid = threadIdx.x;
    const int h = blockIdx.x, b = blockIdx.y;
    const float* cnt_g = content + (size_t)b * D + h * HD;
    const float* cb    = cache + (size_t)b * T * D + h * HD;

    const float pos_param = pos_param_p[0];
    const int e128 = tid & 127;
    const int g4   = tid >> 7;                         // 0..3, wave-uniform
    const int d4   = tid & 31;                         // PV: float4 chunk id
    const int sg   = tid >> 5;                         // PV: s-group 0..15
    float creg = 0.f, bvreg = 0.f;
    if (tid < HD) { creg = cnt_g[tid]; bvreg = bv[h * HD + tid]; }

    float wvreg[32];                     // Wv[g4*32+i][e128], loaded post-B2

    if (tid < 256) {
        // ===== C-waves 0-3 =====
        const int g2 = g4;                             // 0/1
        // Wk prefetch: thread (d=e128, eh=g2) holds Wk[d][g2*64 .. +63]
        float4 wk4[16];
        {
            const float* wkp = Wk + h * HD * HD + e128 * HD + g2 * 64;
            #pragma unroll
            for (int j = 0; j < 16; ++j) wk4[j] = *(const float4*)(wkp + j * 4);
        }
        // q partial: q[e] = sum_d cnt[d] * Wq[d][e] (+ bq on g2==0 half)
        const float* wqp = Wq + h * HD * HD + (g2 * 64) * HD + e128;
        const float* cg  = cnt_g + g2 * 64;            // wave-uniform reads
        float acc = (g2 == 0) ? bq[h * HD + e128] : 0.f;
        #pragma unroll
        for (int i = 0; i < 64; ++i)
            acc = fmaf(cg[i], wqp[i * HD], acc);
        qp[g2][e128] = acc;

        __syncthreads();   // B1: q partials + window staged

        // qk partial: thread (d=e128, eh=g2) over e = g2*64..+63
        float a2 = 0.f;
        #pragma unroll
        for (int j = 0; j < 16; ++j) {
            const float4 q0 = *(const float4*)&qp[0][g2 * 64 + j * 4]; // broadcast
            const float4 q1 = *(const float4*)&qp[1][g2 * 64 + j * 4];
            a2 = fmaf(wk4[j].x, q0.x + q1.x, a2);
            a2 = fmaf(wk4[j].y, q0.y + q1.y, a2);
            a2 = fmaf(wk4[j].z, q0.z + q1.z, a2);
            a2 = fmaf(wk4[j].w, q0.w + q1.w, a2);
        }
        kp[g2][e128] = a2;
    } else {
        // ===== S-waves 4-7: window staging only pre-B1 =====
        // 32 async 1KB global_load_lds per wave. LDS dest linear
        // (base + lane*16); per-lane source pre-swizzled so lds chunk c
        // holds global chunk f = c ^ (row&7).
        const int sw   = (tid >> 6) - 4;               // 0..3
        const int lane = tid & 63;
        #pragma unroll
        for (int i = 0; i < 32; ++i) {
            const int w    = sw * 64 + i * 2;          // wave-uniform row pair
            const int row  = w + (lane >> 5);
            const int f    = (lane & 31) ^ (row & 7);
            const int gpos = cutoff + row;
            const float* src = (gpos < T) ? (cb + (size_t)gpos * D + f * 4)
                                          : (cnt_g + f * 4);
            __builtin_amdgcn_global_load_lds((gfloat*)src, (lfloat*)&xs[w << 7],
                                             16, 0, 0);
        }
        __syncthreads();   // B1 (drains vmcnt -> xs complete)
    }
    __syncthreads();       // B2: kp ready

    // ---- all waves: issue Wv quarter now; lands under scores/softmax ----
    {
        const float* wvp = Wv + h * HD * HD + (g4 * 32) * HD + e128;
        #pragma unroll
        for (int i = 0; i < 32; ++i) wvreg[i] = wvp[i * HD];
    }

    // ---- kfull = kp[0] + kp[1], once (saves a ds_read per j in scores) ----
    if (tid < HD) kfull[tid] = kp[0][tid] + kp[1][tid];
    __syncthreads();   // B2b

    // ---- scores (512 threads = 256 s x 2 d-halves) ----
    {
        const int s = tid & 255, dh = tid >> 8;        // dh wave-uniform
        const int swz = s & 7;
        float acc = 0.f;
        #pragma unroll
        for (int j = 0; j < 16; ++j) {
            const int c = (dh * 16 + j) ^ swz;
            const float4 x  = *(const float4*)&xs[(s << 7) + (c << 2)];
            const float4 kf = *(const float4*)&kfull[dh * 64 + j * 4]; // broadcast
            acc = fmaf(x.x, kf.x, acc);
            acc = fmaf(x.y, kf.y, acc);
            acc = fmaf(x.z, kf.z, acc);
            acc = fmaf(x.w, kf.w, acc);
        }
        scp[dh][s] = acc;
    }
    __syncthreads();   // B3

    // ---- softmax weights, no max reduction (subtract the constant NEG) ----
    float p = 0.f;
    if (tid < WIN) {
        const float dot = scp[0][tid] + scp[1][tid];
        const int n = (WIN - 1) - tid;                 // distance to query
        float posb;
        if (n < 16) {
            posb = (float)n;
        } else {
            const float lc = 2.0794415416798357f;      // float32(log(8))
            int large = 16 + (int)((logf((float)n / 16.0f) / lc) * 16.0f);
            if (large > 31) large = 31;
            posb = (float)large;
        }
        // time_mask collapses to NEG everywhere (1->0, then 0->NEG); +NEG
        // reproduces the reference's pre-softmax quantization, and
        // (y + NEG) - NEG is exact in fp32; constant factor cancels in 1/SUM.
        const float score = (dot / 11.313708498984761f) - pos_param * posb + NEG;
        p = expf(score - NEG);
        sc[tid] = p;
    }
    float ssum = p;
    #pragma unroll
    for (int off = 32; off >= 1; off >>= 1) ssum += __shfl_xor(ssum, off);
    if ((tid & 63) == 0) red2[tid >> 6] = ssum;
    __syncthreads();   // B5: sc + red2 ready

    // ---- PV: wsum_d partials, b128 reads (32 d-chunks x 16 s-groups) ----
    {
        float4 wacc = make_float4(0.f, 0.f, 0.f, 0.f);
        #pragma unroll
        for (int ii = 0; ii < 4; ++ii) {
            const float4 ps = *(const float4*)&sc[sg * 16 + ii * 4]; // broadcast
            const float pw[4] = { ps.x, ps.y, ps.z, ps.w };
            #pragma unroll
            for (int k = 0; k < 4; ++k) {
                const int r = sg * 16 + ii * 4 + k;
                const int c = d4 ^ (r & 7);
                const float4 x = *(const float4*)&xs[(r << 7) + (c << 2)];
                wacc.x = fmaf(pw[k], x.x, wacc.x);
                wacc.y = fmaf(pw[k], x.y, wacc.y);
                wacc.z = fmaf(pw[k], x.z, wacc.z);
                wacc.w = fmaf(pw[k], x.w, wacc.w);
            }
        }
        *(float4*)&wp[sg][d4 << 2] = wacc;
    }
    __syncthreads();   // B6 (wp written)

    if (tid < HD) {
        float t = 0.f;
        #pragma unroll
        for (int s2 = 0; s2 < 16; ++s2) t += wp[s2][tid];   // 2 lanes/bank: free
        ws[tid] = t;
    }
    __syncthreads();   // B6b (ws ready)

    // ---- out quarter: op[g4][e] = sum_{i<32} ws[g4*32+i] * Wv[g4*32+i][e] ----
    {
        float acc = 0.f;
        #pragma unroll
        for (int i = 0; i < 32; ++i)
            acc = fmaf(ws[g4 * 32 + i], wvreg[i], acc);     // ws broadcast read
        op[g4][e128] = acc;
    }
    __syncthreads();   // B7

    if (tid < HD) {
        float SUM = red2[0];
        #pragma unroll
        for (int i = 1; i < 8; ++i) SUM += red2[i];
        const float r = (op[0][tid] + op[1][tid] + op[2][tid] + op[3][tid])
                        * (1.0f / SUM) + bvreg + creg;
        out[(size_t)b * D + h * HD + tid] = r;
    }
}

// ---------------- generic fallback (any window<=256) ----------
__global__ __launch_bounds__(256) void bca_generic(
    const float* __restrict__ content, const float* __restrict__ cache,
    const float* __restrict__ Wq, const float* __restrict__ bq,
    const float* __restrict__ Wk, const float* __restrict__ Wv,
    const float* __restrict__ bv, const float* __restrict__ pos_param_p,
    float* __restrict__ out,
    int B, int T, int D, int H, int S, int window, int cutoff)
{
    constexpr int HD = 128;
    constexpr int XP = HD + 1;
    const int bh = blockIdx.x;
    const int b = bh / H, h = bh % H;
    const int tid = threadIdx.x;

    __shared__ float xs[WINDOW_MAX * XP];
    __shared__ float cnt_s[HD];
    __shared__ float q_s[HD];
    __shared__ float qk_s[HD];
    __shared__ float sc_s[WINDOW_MAX];
    __shared__ float part_s[256];
    __shared__ float wsum_s[HD];
    __shared__ float red_s[4];

    const float* cnt_g = content + (size_t)b * D + (size_t)h * HD;
    if (tid < HD) cnt_s[tid] = cnt_g[tid];

    const int total4 = window * (HD / 4);
    for (int idx = tid; idx < total4; idx += blockDim.x) {
        const int w = idx >> 5, f = idx & 31;
        const int gpos = cutoff + w;
        const float* src = (gpos < T)
            ? (cache + (size_t)b * T * D + (size_t)gpos * D + (size_t)h * HD)
            : cnt_g;
        const float4 v4 = *(const float4*)(src + f * 4);
        float* dst = &xs[w * XP + f * 4];
        dst[0] = v4.x; dst[1] = v4.y; dst[2] = v4.z; dst[3] = v4.w;
    }
    __syncthreads();

    if (tid < HD) {
        const float* wq = Wq + (size_t)h * HD * HD;
        float acc = 0.f;
        #pragma unroll 8
        for (int d = 0; d < HD; ++d) acc = fmaf(cnt_s[d], wq[d * HD + tid], acc);
        q_s[tid] = acc + bq[h * HD + tid];
    }
    __syncthreads();

    if (tid < HD) {
        const float* wk = Wk + (size_t)h * HD * HD + (size_t)tid * HD;
        float acc = 0.f;
        #pragma unroll 8
        for (int e = 0; e < HD; e += 4) {
            const float4 w4 = *(const float4*)(wk + e);
            acc = fmaf(w4.x, q_s[e],     acc);
            acc = fmaf(w4.y, q_s[e + 1], acc);
            acc = fmaf(w4.z, q_s[e + 2], acc);
            acc = fmaf(w4.w, q_s[e + 3], acc);
        }
        qk_s[tid] = acc;
    }
    __syncthreads();

    const float pos_param = pos_param_p[0];
    float score = -INFINITY;
    if (tid < window) {
        float acc = 0.f;
        const float* xr = &xs[tid * XP];
        #pragma unroll 8
        for (int d = 0; d < HD; ++d) acc = fmaf(qk_s[d], xr[d], acc);
        const int gpos = cutoff + tid;
        const int n = (S - 1) - gpos;
        float posb;
        if (n < 16) posb = (float)n;
        else {
            const float lc = 2.0794415416798357f;
            int large = 16 + (int)((logf((float)n / 16.0f) / lc) * 16.0f);
            if (large > 31) large = 31;
            posb = (float)large;
        }
        score = (acc / 11.313708498984761f) - pos_param * posb + NEG;
    }

    float m = score;
    #pragma unroll
    for (int off = 32; off >= 1; off >>= 1) m = fmaxf(m, __shfl_xor(m, off));
    if ((tid & 63) == 0) red_s[tid >> 6] = m;
    __syncthreads();
    const int nw = blockDim.x >> 6;
    float M = red_s[0];
    for (int i = 1; i < nw; ++i) M = fmaxf(M, red_s[i]);

    float p = (tid < window) ? expf(score - M) : 0.f;
    float ssum = p;
    #pragma unroll
    for (int off = 32; off >= 1; off >>= 1) ssum += __shfl_xor(ssum, off);
    __syncthreads();
    if ((tid & 63) == 0) red_s[tid >> 6] = ssum;
    __syncthreads();
    float SUM = 0.f;
    for (int i = 0; i < nw; ++i) SUM += red_s[i];
    const float inv = 1.0f / SUM;
    if (tid < window) sc_s[tid] = p * inv;
    __syncthreads();

    {
        const int d = tid & (HD - 1), half = tid >> 7;
        const int s0 = half * (window >> 1), s1 = s0 + (window >> 1);
        float acc = 0.f;
        for (int s = s0; s < s1; ++s) acc = fmaf(sc_s[s], xs[s * XP + d], acc);
        part_s[tid] = acc;
    }
    __syncthreads();
    if (tid < HD) wsum_s[tid] = part_s[tid] + part_s[tid + HD];
    __syncthreads();

    {
        const int e = tid & (HD - 1), dh = tid >> 7;
        const float* wv = Wv + (size_t)h * HD * HD;
        float acc = 0.f;
        for (int d = dh * 64; d < dh * 64 + 64; ++d)
            acc = fmaf(wsum_s[d], wv[d * HD + e], acc);
        part_s[tid] = acc;
    }
    __syncthreads();
    if (tid < HD) {
        const float r = part_s[tid] + part_s[tid + HD]
                      + bv[h * HD + tid] + cnt_g[tid];
        out[(size_t)b * D + (size_t)h * HD + tid] = r;
    }
}

extern "C" void kernel_launch(void* const* d_in, const int* in_sizes, int n_in,
                              void* d_out, int out_size, void* d_ws, size_t ws_size,
                              hipStream_t stream) {
    // inputs: 0:t 1:content_t 2:time_mask 3:cache 4:speakers 5:Wq 6:bq 7:Wk 8:bk 9:Wv 10:bv 11:pos_param
    const float* content = (const float*)d_in[1];
    const float* cache   = (const float*)d_in[3];
    const float* Wq      = (const float*)d_in[5];
    const float* bq      = (const float*)d_in[6];
    const float* Wk      = (const float*)d_in[7];
    const float* Wv      = (const float*)d_in[9];
    const float* bv      = (const float*)d_in[10];
    const float* posp    = (const float*)d_in[11];

    const int D  = in_sizes[6];
    const int B  = in_sizes[1] / D;
    const int hd = in_sizes[5] / D;
    const int H  = D / hd;
    const int T  = in_sizes[3] / (B * D);
    const int S  = T + 1;
    const int window = (S < WINDOW_MAX) ? S : WINDOW_MAX;
    const int cutoff = S - window;

    if (window == WINDOW_MAX && hd == 128) {
        dim3 grid(H, B), block(512);
        hipLaunchKernelGGL(bca_fast, grid, block, 0, stream,
                           content, cache, Wq, bq, Wk, Wv, bv, posp,
                           (float*)d_out, B, T, D, H, S, cutoff);
    } else {
        dim3 grid(B * H), block(256);
        hipLaunchKernelGGL(bca_generic, grid, block, 0, stream,
                           content, cache, Wq, bq, Wk, Wv, bv, posp,
                           (float*)d_out, B, T, D, H, S, window, cutoff);
    }
}